// Round 3
// baseline (88.102 us; speedup 1.0000x reference)
//
#include <hip/hip_runtime.h>
#include <stdint.h>

#define IN_F   4096   // output width / weight cols
#define OUT_F  4096   // x width / weight rows
#define BATCH  8192
#define CHUNKS 256
#define ROWS_PER_CHUNK (OUT_F / CHUNKS)   // 16

__device__ __forceinline__ uint32_t fkey(float v) {
    // monotone float -> uint mapping (order-preserving for all finite values)
    uint32_t u = __float_as_uint(v);
    return (u & 0x80000000u) ? ~u : (u | 0x80000000u);
}

// Zero-init the packed argmax buffer (4096 u64). Must run every call:
// harness poisons ws once and never re-poisons between replays.
__global__ __launch_bounds__(256) void init_packed(unsigned long long* __restrict__ p) {
    p[blockIdx.x * 256 + threadIdx.x] = 0ull;
}

// Column-argmax over a 16-row chunk, then atomicMax into packed[c].
// pack = (fkey(val) << 32) | ~row  ->  u64 max == (max val, then MIN row = first occurrence)
// grid (4, 256), block 256: 1024 blocks = 4/CU.
__global__ __launch_bounds__(256) void argmax_atomic(
        const float* __restrict__ w,
        unsigned long long* __restrict__ packed) {
    int c4 = blockIdx.x * 256 + threadIdx.x;      // float4-column index [0, 1024)
    int r0 = blockIdx.y * ROWS_PER_CHUNK;
    const float4* w4 = (const float4*)w;
    float b0 = -INFINITY, b1 = -INFINITY, b2 = -INFINITY, b3 = -INFINITY;
    int i0 = 0, i1 = 0, i2 = 0, i3 = 0;
    #pragma unroll
    for (int k = 0; k < ROWS_PER_CHUNK; ++k) {
        int r = r0 + k;
        float4 v = w4[(size_t)r * (IN_F / 4) + c4];
        if (v.x > b0) { b0 = v.x; i0 = r; }       // '>' keeps FIRST occurrence
        if (v.y > b1) { b1 = v.y; i1 = r; }
        if (v.z > b2) { b2 = v.z; i2 = r; }
        if (v.w > b3) { b3 = v.w; i3 = r; }
    }
    int c = c4 * 4;
    atomicMax(&packed[c + 0], ((unsigned long long)fkey(b0) << 32) | (uint32_t)(~i0));
    atomicMax(&packed[c + 1], ((unsigned long long)fkey(b1) << 32) | (uint32_t)(~i1));
    atomicMax(&packed[c + 2], ((unsigned long long)fkey(b2) << 32) | (uint32_t)(~i2));
    atomicMax(&packed[c + 3], ((unsigned long long)fkey(b3) << 32) | (uint32_t)(~i3));
}

// Gather: 2 rows per block, 512 threads, 32 KiB LDS.
// Stage both rows (contiguous 32 KB, coalesced float4), one barrier, then
// gather from LDS with indices unpacked once and reused for both rows.
__global__ __launch_bounds__(512) void gather2(
        const float* __restrict__ x,
        const unsigned long long* __restrict__ packed,
        float* __restrict__ y) {
    __shared__ float xr[2 * OUT_F];               // 32 KiB
    int b2 = blockIdx.x;                          // row pair index
    const float4* x4 = (const float4*)(x + (size_t)b2 * 2 * OUT_F);
    float4* s4 = (float4*)xr;
    #pragma unroll
    for (int i = 0; i < 4; ++i)                   // 2048 float4 / 512 threads
        s4[i * 512 + threadIdx.x] = x4[i * 512 + threadIdx.x];
    __syncthreads();
    float4* y4 = (float4*)(y + (size_t)b2 * 2 * IN_F);
    #pragma unroll
    for (int g = 0; g < 2; ++g) {
        int j4 = g * 512 + threadIdx.x;           // float4-col group [0, 1024)
        ulonglong2 pa = *(const ulonglong2*)&packed[(size_t)j4 * 4];
        ulonglong2 pb = *(const ulonglong2*)&packed[(size_t)j4 * 4 + 2];
        int id0 = (int)(~(uint32_t)pa.x);
        int id1 = (int)(~(uint32_t)pa.y);
        int id2 = (int)(~(uint32_t)pb.x);
        int id3 = (int)(~(uint32_t)pb.y);
        #pragma unroll
        for (int r = 0; r < 2; ++r) {             // reuse indices for both rows
            float4 o;
            o.x = xr[r * OUT_F + id0];
            o.y = xr[r * OUT_F + id1];
            o.z = xr[r * OUT_F + id2];
            o.w = xr[r * OUT_F + id3];
            y4[r * (IN_F / 4) + j4] = o;
        }
    }
}

extern "C" void kernel_launch(void* const* d_in, const int* in_sizes, int n_in,
                              void* d_out, int out_size, void* d_ws, size_t ws_size,
                              hipStream_t stream) {
    const float* x = (const float*)d_in[0];       // (BATCH, OUT_F)
    const float* w = (const float*)d_in[1];       // (OUT_F, IN_F)
    float* y = (float*)d_out;                     // (BATCH, IN_F)

    unsigned long long* packed = (unsigned long long*)d_ws;   // 4096 u64 = 32 KB

    init_packed<<<IN_F / 256, 256, 0, stream>>>(packed);
    dim3 g1(IN_F / (256 * 4), CHUNKS);
    argmax_atomic<<<g1, 256, 0, stream>>>(w, packed);
    gather2<<<BATCH / 2, 512, 0, stream>>>(x, packed, y);
}